// Round 10
// baseline (364.607 us; speedup 1.0000x reference)
//
#include <hip/hip_runtime.h>

#define N_    2048
#define H_    128
#define B_    4
#define CIN_  3
#define COUT_ 3
#define LOG2E 1.44269504089f

// ---------- helpers ----------
__device__ __forceinline__ float gelu_tanh(float x) {
    // jax.nn.gelu(approximate=True), exp2 domain
    float x2 = x * x;
    float e = __builtin_amdgcn_exp2f(x * fmaf(-0.10294340397f, x2, -2.30220899f));
    return x * __builtin_amdgcn_rcpf(1.0f + e);
}

// ---------- K0: small-weight precompute ----------
// wpack[lvl*256+k] = {W1[lvl,0,k], W1[lvl,1,k], b1[lvl,k], mean_h W2[lvl,k,h]}
__global__ void prep_kernel(const float* __restrict__ W1, const float* __restrict__ b1,
                            const float* __restrict__ W2, const float* __restrict__ b2,
                            const float* __restrict__ Wo, const float* __restrict__ bo,
                            const float* __restrict__ Wout, const float* __restrict__ bout,
                            float4* __restrict__ wpack, float* __restrict__ b2m,
                            float* __restrict__ wf, float* __restrict__ bf) {
    int gid = blockIdx.x * 256 + threadIdx.x;
    if (gid < 768) {
        const float* r = W2 + (size_t)gid * 128;
        float s = 0.f;
        for (int h = 0; h < 128; ++h) s += r[h];
        int lvl = gid >> 8, k = gid & 255;
        wpack[gid] = make_float4(W1[lvl * 512 + k], W1[lvl * 512 + 256 + k],
                                 b1[gid], s * (1.0f / 128.0f));
    } else if (gid < 771) {
        int lvl = gid - 768;
        const float* r = b2 + lvl * 128;
        float s = 0.f;
        for (int h = 0; h < 128; ++h) s += r[h];
        b2m[lvl] = s * (1.0f / 128.0f);
    } else if (gid >= 1024 && gid < 1408) {
        int e = gid - 1024;
        int h = e / 3, c = e - 3 * h;
        float s = 0.f;
        for (int j = 0; j < 128; ++j) s = fmaf(Wo[h * 128 + j], Wout[j * 3 + c], s);
        wf[e] = s;
    } else if (gid >= 1408 && gid < 1411) {
        int c = gid - 1408;
        float s = bout[c];
        for (int j = 0; j < 128; ++j) s = fmaf(bo[j], Wout[j * 3 + c], s);
        bf[c] = s;
    }
}

// ---------- K1: full wavelet pyramid for one (b,h) row, all in LDS ----------
__global__ __launch_bounds__(256) void wavelet_fused_kernel(
        const float* __restrict__ x, const float* __restrict__ Win,
        const float* __restrict__ b_in,
        const float* __restrict__ wlow, const float* __restrict__ whigh,
        const float4* __restrict__ wpack, const float* __restrict__ b2m,
        float* __restrict__ r0g) {
    __shared__ float cur[2048];
    __shared__ float aA[1024];
    __shared__ float pp0[1024];
    __shared__ float aB[512];
    __shared__ float pp1[512];
    __shared__ float pp2[256];
    __shared__ float r2s[512];
    __shared__ float r1s[1024];
    int tid = threadIdx.x;
    int m = blockIdx.x;
    int b = m >> 7, h = m & 127;
    float w0 = Win[h], w1 = Win[128 + h], w2 = Win[256 + h];
    float bi = b_in[h];
    float wl[8], wh[8];
#pragma unroll
    for (int t = 0; t < 8; ++t) { wl[t] = wlow[t]; wh[t] = whigh[t]; }

    // S1: input projection row
    const float* xr = x + (size_t)b * (CIN_ * N_);
    for (int idx = tid; idx < 2048; idx += 256) {
        float v = bi;
        v = fmaf(xr[idx], w0, v);
        v = fmaf(xr[N_ + idx], w1, v);
        v = fmaf(xr[2 * N_ + idx], w2, v);
        cur[idx] = v;
    }
    __syncthreads();

    // S2: level-0 DWT + MLP (4 coeffs/thread)
    {
        float a4[4], d4[4], acc4[4];
#pragma unroll
        for (int u = 0; u < 4; ++u) {
            int i = tid + u * 256;
            int j0 = 2 * i - 4;
            float a = 0.f, d = 0.f;
#pragma unroll
            for (int t = 0; t < 8; ++t) {
                int j = j0 + t;
                float xv = ((unsigned)j < 2048u) ? cur[j] : 0.f;
                a = fmaf(xv, wl[7 - t], a);
                d = fmaf(xv, wh[7 - t], d);
            }
            a4[u] = a; d4[u] = d; aA[i] = a; acc4[u] = 0.f;
        }
#pragma unroll 4
        for (int kk = 0; kk < 256; ++kk) {
            float4 w = wpack[kk];
#pragma unroll
            for (int u = 0; u < 4; ++u) {
                float t = fmaf(a4[u], w.x, fmaf(d4[u], w.y, w.z));
                acc4[u] = fmaf(gelu_tanh(t), w.w, acc4[u]);
            }
        }
        float bb = b2m[0];
#pragma unroll
        for (int u = 0; u < 4; ++u) pp0[tid + u * 256] = acc4[u] + bb;
    }
    __syncthreads();

    // S3: level-1 DWT + MLP (2 coeffs/thread)
    {
        float a2v[2], d2v[2], acc2[2];
#pragma unroll
        for (int u = 0; u < 2; ++u) {
            int i = tid + u * 256;
            int j0 = 2 * i - 4;
            float a = 0.f, d = 0.f;
#pragma unroll
            for (int t = 0; t < 8; ++t) {
                int j = j0 + t;
                float xv = ((unsigned)j < 1024u) ? aA[j] : 0.f;
                a = fmaf(xv, wl[7 - t], a);
                d = fmaf(xv, wh[7 - t], d);
            }
            a2v[u] = a; d2v[u] = d; aB[i] = a; acc2[u] = 0.f;
        }
#pragma unroll 4
        for (int kk = 0; kk < 256; ++kk) {
            float4 w = wpack[256 + kk];
#pragma unroll
            for (int u = 0; u < 2; ++u) {
                float t = fmaf(a2v[u], w.x, fmaf(d2v[u], w.y, w.z));
                acc2[u] = fmaf(gelu_tanh(t), w.w, acc2[u]);
            }
        }
        float bb = b2m[1];
#pragma unroll
        for (int u = 0; u < 2; ++u) pp1[tid + u * 256] = acc2[u] + bb;
    }
    __syncthreads();

    // S4: level-2 DWT + MLP (1 coeff/thread); approx not needed
    {
        int j0 = 2 * tid - 4;
        float a = 0.f, d = 0.f;
#pragma unroll
        for (int t = 0; t < 8; ++t) {
            int j = j0 + t;
            float xv = ((unsigned)j < 512u) ? aB[j] : 0.f;
            a = fmaf(xv, wl[7 - t], a);
            d = fmaf(xv, wh[7 - t], d);
        }
        float acc = 0.f;
#pragma unroll 4
        for (int kk = 0; kk < 256; ++kk) {
            float4 w = wpack[512 + kk];
            float t = fmaf(a, w.x, fmaf(d, w.y, w.z));
            acc = fmaf(gelu_tanh(t), w.w, acc);
        }
        pp2[tid] = acc + b2m[2];
    }
    __syncthreads();

    // S5: r2 = idwt(pp2, pp2)
#pragma unroll
    for (int u = 0; u < 2; ++u) {
        int ii = tid + u * 256;
        int podd = ii & 1;
        int off0 = (ii >> 1) - 2 + podd;
        float r = 0.f;
#pragma unroll
        for (int s = 0; s < 4; ++s) {
            int idx = off0 + s;
            float av = ((unsigned)idx < 256u) ? pp2[idx] : 0.f;
            r = fmaf(av, wl[2 * s + podd] + wh[2 * s + podd], r);
        }
        r2s[ii] = r;
    }
    __syncthreads();

    // S6: r1 = idwt(r2s, pp1)
#pragma unroll
    for (int u = 0; u < 4; ++u) {
        int ii = tid + u * 256;
        int podd = ii & 1;
        int off0 = (ii >> 1) - 2 + podd;
        float r = 0.f;
#pragma unroll
        for (int s = 0; s < 4; ++s) {
            int idx = off0 + s;
            bool ok = (unsigned)idx < 512u;
            float av = ok ? r2s[idx] : 0.f;
            float dv = ok ? pp1[idx] : 0.f;
            r = fmaf(av, wl[2 * s + podd], r);
            r = fmaf(dv, wh[2 * s + podd], r);
        }
        r1s[ii] = r;
    }
    __syncthreads();

    // S7: r0 = idwt(r1s, pp0) -> global
    float* orow = r0g + (size_t)m * 2048;
#pragma unroll
    for (int u = 0; u < 8; ++u) {
        int ii = tid + u * 256;
        int podd = ii & 1;
        int off0 = (ii >> 1) - 2 + podd;
        float r = 0.f;
#pragma unroll
        for (int s = 0; s < 4; ++s) {
            int idx = off0 + s;
            bool ok = (unsigned)idx < 1024u;
            float av = ok ? r1s[idx] : 0.f;
            float dv = ok ? pp0[idx] : 0.f;
            r = fmaf(av, wl[2 * s + podd], r);
            r = fmaf(dv, wh[2 * s + podd], r);
        }
        orow[ii] = r;
    }
}

// ---------- K5: QKV projection ----------
__global__ __launch_bounds__(384) void qkv_kernel(
        const float* __restrict__ r0,
        const float* __restrict__ Wq, const float* __restrict__ bq,
        const float* __restrict__ Wk, const float* __restrict__ bk,
        const float* __restrict__ Wv, const float* __restrict__ bv,
        float* __restrict__ qB, float* __restrict__ kB, float* __restrict__ vB) {
    int tid = threadIdx.x;
    int rowbase = blockIdx.x * 16;       // row = b*N + n
    int b  = rowbase >> 11;
    int n0 = rowbase & 2047;

    const float* W; const float* bias; float* dst; int jj;
    if (tid < 128)      { W = Wq; bias = bq; dst = qB; jj = tid; }
    else if (tid < 256) { W = Wk; bias = bk; dst = kB; jj = tid - 128; }
    else                { W = Wv; bias = bv; dst = vB; jj = tid - 256; }

    const float* abase = r0 + (size_t)b * (H_ * N_) + n0;
    float acc[16];
#pragma unroll
    for (int r = 0; r < 16; ++r) acc[r] = 0.f;
#pragma unroll 4
    for (int h = 0; h < 128; ++h) {
        float w = W[h * 128 + jj];
        const float* ar = abase + (size_t)h * N_;
#pragma unroll
        for (int r = 0; r < 16; ++r) acc[r] = fmaf(ar[r], w, acc[r]);
    }
    float bb = bias[jj];
    int head = jj >> 4, t = jj & 15;
    size_t obase = ((size_t)(b * 8 + head) * N_) * 16 + t;
#pragma unroll
    for (int r = 0; r < 16; ++r)
        dst[obase + (size_t)(n0 + r) * 16] = acc[r] + bb;
}

// ---------- K6: flash attention, split-K, 4 q/lane; K via LDS, V via global (VMEM pipe) ----------
#define DOT4(acc, qq, aa) do { acc = fmaf(qq.x, aa.x, acc); acc = fmaf(qq.y, aa.y, acc); \
                               acc = fmaf(qq.z, aa.z, acc); acc = fmaf(qq.w, aa.w, acc); } while (0)
#define SCALE4(oo, c)     do { oo.x *= c; oo.y *= c; oo.z *= c; oo.w *= c; } while (0)
#define AXPY4(oo, p, aa)  do { oo.x = fmaf(p, aa.x, oo.x); oo.y = fmaf(p, aa.y, oo.y); \
                               oo.z = fmaf(p, aa.z, oo.z); oo.w = fmaf(p, aa.w, oo.w); } while (0)

template<int KS>
__global__ __launch_bounds__(128, 2) void attn_kernel(
        const float* __restrict__ qb, const float* __restrict__ kb,
        const float* __restrict__ vb,
        float* __restrict__ part_o, float* __restrict__ part_ml) {
    __shared__ float4 kt4[512];   // K only: 128 keys x 16 floats (8 KB)
    int tid   = threadIdx.x;
    int blk   = blockIdx.x;        // bh*(4*KS) + qblk*KS + split
    int split = blk % KS;
    int qblk  = (blk / KS) & 3;
    int bh    = blk / (4 * KS);

    const float4* ksrc = (const float4*)(kb + (size_t)bh * (N_ * 16));
    const float sc = 0.25f * LOG2E;

    float4 q[4][4];
    float  m[4], l[4];
    float4 o[4][4];
#pragma unroll
    for (int qi = 0; qi < 4; ++qi) {
        const float4* qr = (const float4*)(qb + ((size_t)bh * N_ + qblk * 512 + qi * 128 + tid) * 16);
#pragma unroll
        for (int j = 0; j < 4; ++j) { q[qi][j] = qr[j]; SCALE4(q[qi][j], sc); }
        m[qi] = -3.0e38f; l[qi] = 0.f;
#pragma unroll
        for (int j = 0; j < 4; ++j) o[qi][j] = make_float4(0.f, 0.f, 0.f, 0.f);
    }

    int k0 = split * (N_ / KS);
    for (int t0 = k0; t0 < k0 + N_ / KS; t0 += 128) {
        __syncthreads();
        const float4* ks = ksrc + t0 * 4;
#pragma unroll
        for (int u = 0; u < 4; ++u)
            kt4[tid + u * 128] = ks[tid + u * 128];
        __syncthreads();

        // V tile base with a shuffle-laundered (divergence-opaque) index: value
        // equals t0 but the compiler cannot prove uniformity, so V reads stay on
        // the VMEM pipe (per-lane global_load_dwordx4, broadcast L1 hits) instead
        // of being scalarized (round-6 regression) or staged in LDS (pipe wall).
        int tdiv = __shfl(t0, 0);
        const float4* vtile = (const float4*)(vb + (size_t)bh * (N_ * 16)) + (size_t)tdiv * 4;

        for (int c0 = 0; c0 < 128; c0 += 4) {
            float sv[4][4];
            float cm[4] = {-3.0e38f, -3.0e38f, -3.0e38f, -3.0e38f};
#pragma unroll
            for (int c = 0; c < 4; ++c) {
                int kr = (c0 + c) * 4;
                float4 k0v = kt4[kr], k1v = kt4[kr+1], k2v = kt4[kr+2], k3v = kt4[kr+3];
#pragma unroll
                for (int qi = 0; qi < 4; ++qi) {
                    float s0 = 0.f, s1 = 0.f;
                    DOT4(s0, q[qi][0], k0v); DOT4(s1, q[qi][1], k1v);
                    DOT4(s0, q[qi][2], k2v); DOT4(s1, q[qi][3], k3v);
                    sv[qi][c] = s0 + s1;
                    cm[qi] = fmaxf(cm[qi], sv[qi][c]);
                }
            }
            bool need = (cm[0] > m[0] + 8.f) || (cm[1] > m[1] + 8.f) ||
                        (cm[2] > m[2] + 8.f) || (cm[3] > m[3] + 8.f);
            if (__any(need)) {
#pragma unroll
                for (int qi = 0; qi < 4; ++qi) {
                    float mn = fmaxf(m[qi], cm[qi]);
                    float cr = __builtin_amdgcn_exp2f(m[qi] - mn);
                    l[qi] *= cr;
#pragma unroll
                    for (int j = 0; j < 4; ++j) SCALE4(o[qi][j], cr);
                    m[qi] = mn;
                }
            }
#pragma unroll
            for (int c = 0; c < 4; ++c) {
                int vr = (c0 + c) * 4;
                float4 v0 = vtile[vr], v1 = vtile[vr+1], v2 = vtile[vr+2], v3 = vtile[vr+3];
#pragma unroll
                for (int qi = 0; qi < 4; ++qi) {
                    float p = __builtin_amdgcn_exp2f(sv[qi][c] - m[qi]);
                    l[qi] += p;
                    AXPY4(o[qi][0], p, v0); AXPY4(o[qi][1], p, v1);
                    AXPY4(o[qi][2], p, v2); AXPY4(o[qi][3], p, v3);
                }
            }
        }
    }
#pragma unroll
    for (int qi = 0; qi < 4; ++qi) {
        int qg = bh * N_ + qblk * 512 + qi * 128 + tid;
        float4* po = (float4*)part_o + ((size_t)split * 65536 + qg) * 4;
        po[0] = o[qi][0]; po[1] = o[qi][1]; po[2] = o[qi][2]; po[3] = o[qi][3];
        ((float2*)part_ml)[(size_t)split * 65536 + qg] = make_float2(m[qi], l[qi]);
    }
}

// ---------- K6b: split-K combine fused with final projection ----------
template<int KS>
__global__ __launch_bounds__(128) void combine_final_kernel(
        const float* __restrict__ part_o, const float* __restrict__ part_ml,
        const float* __restrict__ wf, const float* __restrict__ bf,
        float* __restrict__ out) {
    __shared__ float ysh[16 * 129];
    int tid = threadIdx.x;
    int b = blockIdx.x >> 7, nb = blockIdx.x & 127;
    int head = tid >> 4, nl = tid & 15;
    int n = nb * 16 + nl;
    int qg = (b * 8 + head) * N_ + n;

    float m[KS], l[KS];
    float M = -3.0e38f;
#pragma unroll
    for (int s = 0; s < KS; ++s) {
        float2 ml = ((const float2*)part_ml)[(size_t)s * 65536 + qg];
        m[s] = ml.x; l[s] = ml.y;
        M = fmaxf(M, m[s]);
    }
    float w[KS], lt = 0.f;
#pragma unroll
    for (int s = 0; s < KS; ++s) {
        w[s] = __builtin_amdgcn_exp2f(m[s] - M);
        lt = fmaf(l[s], w[s], lt);
    }
    float inv = __builtin_amdgcn_rcpf(lt);
    float o[16];
#pragma unroll
    for (int j = 0; j < 16; ++j) o[j] = 0.f;
#pragma unroll
    for (int s = 0; s < KS; ++s) {
        const float4* po = (const float4*)part_o + ((size_t)s * 65536 + qg) * 4;
#pragma unroll
        for (int r = 0; r < 4; ++r) {
            float4 v = po[r];
            o[4*r+0] = fmaf(v.x, w[s], o[4*r+0]);
            o[4*r+1] = fmaf(v.y, w[s], o[4*r+1]);
            o[4*r+2] = fmaf(v.z, w[s], o[4*r+2]);
            o[4*r+3] = fmaf(v.w, w[s], o[4*r+3]);
        }
    }
    int col = head * 16;
#pragma unroll
    for (int j = 0; j < 16; ++j) ysh[nl * 129 + col + j] = o[j] * inv;
    __syncthreads();
    if (tid < 48) {
        int c = tid >> 4, nl2 = tid & 15;
        float acc = bf[c];
        const float* yr = ysh + nl2 * 129;
#pragma unroll 4
        for (int h = 0; h < 128; ++h) acc = fmaf(yr[h], wf[h * 3 + c], acc);
        out[((size_t)b * 3 + c) * N_ + nb * 16 + nl2] = acc;
    }
}

// ---------- launch ----------
extern "C" void kernel_launch(void* const* d_in, const int* in_sizes, int n_in,
                              void* d_out, int out_size, void* d_ws, size_t ws_size,
                              hipStream_t stream) {
    const float* x    = (const float*)d_in[0];
    const float* wlow = (const float*)d_in[1];
    const float* whigh= (const float*)d_in[2];
    const float* Win  = (const float*)d_in[3];
    const float* b_in = (const float*)d_in[4];
    const float* W1   = (const float*)d_in[5];
    const float* b1   = (const float*)d_in[6];
    const float* W2   = (const float*)d_in[7];
    const float* b2   = (const float*)d_in[8];
    const float* Wq   = (const float*)d_in[9];
    const float* bq   = (const float*)d_in[10];
    const float* Wk   = (const float*)d_in[11];
    const float* bk   = (const float*)d_in[12];
    const float* Wv   = (const float*)d_in[13];
    const float* bv   = (const float*)d_in[14];
    const float* Wo   = (const float*)d_in[15];
    const float* bo   = (const float*)d_in[16];
    const float* Wout = (const float*)d_in[17];
    const float* bout = (const float*)d_in[18];
    float* out = (float*)d_out;
    (void)in_sizes; (void)n_in; (void)out_size;

    float* ws = (float*)d_ws;
    // persistent: q/k/v buffers, each B*HEADS*N*dh = 1,048,576 floats
    float* qBuf  = ws;
    float* kBuf  = ws + 1048576;
    float* vBuf  = ws + 2097152;
    float* base2 = ws + 3145728;
    // r0 (dead after qkv) overlays the attention partials region
    float* r0    = base2;              // 1,048,576 floats

    // choose split-K by available workspace (constant across calls)
    const size_t need16 = (3145728ull + 16ull * 1048576 + 16ull * 131072 + 4096ull) * 4;
    const size_t need8  = (3145728ull +  8ull * 1048576 +  8ull * 131072 + 4096ull) * 4;
    int KS = (ws_size >= need16) ? 16 : ((ws_size >= need8) ? 8 : 4);

    float* part_o  = base2;                              // KS * 1048576 floats
    float* part_ml = base2 + (size_t)KS * 1048576;       // KS * 131072 floats
    float* smalls  = part_ml + (size_t)KS * 131072;
    float4* wpack = (float4*)smalls;                     // 768 float4 = 3072 floats
    float* b2m = smalls + 3072;                          // 3
    float* wf  = smalls + 3088;                          // 384
    float* bf  = smalls + 3472;                          // 3

    prep_kernel<<<8, 256, 0, stream>>>(W1, b1, W2, b2, Wo, bo, Wout, bout, wpack, b2m, wf, bf);

    wavelet_fused_kernel<<<512, 256, 0, stream>>>(x, Win, b_in, wlow, whigh,
                                                  wpack, b2m, r0);

    qkv_kernel<<<512, 384, 0, stream>>>(r0, Wq, bq, Wk, bk, Wv, bv, qBuf, kBuf, vBuf);

    if (KS == 16) {
        attn_kernel<16><<<32 * 4 * 16, 128, 0, stream>>>(qBuf, kBuf, vBuf, part_o, part_ml);
        combine_final_kernel<16><<<512, 128, 0, stream>>>(part_o, part_ml, wf, bf, out);
    } else if (KS == 8) {
        attn_kernel<8><<<32 * 4 * 8, 128, 0, stream>>>(qBuf, kBuf, vBuf, part_o, part_ml);
        combine_final_kernel<8><<<512, 128, 0, stream>>>(part_o, part_ml, wf, bf, out);
    } else {
        attn_kernel<4><<<32 * 4 * 4, 128, 0, stream>>>(qBuf, kBuf, vBuf, part_o, part_ml);
        combine_final_kernel<4><<<512, 128, 0, stream>>>(part_o, part_ml, wf, bf, out);
    }
}

// Round 12
// 339.597 us; speedup vs baseline: 1.0736x; 1.0736x over previous
//
#include <hip/hip_runtime.h>

#define N_    2048
#define H_    128
#define B_    4
#define CIN_  3
#define COUT_ 3
#define LOG2E 1.44269504089f

// ---------- helpers ----------
__device__ __forceinline__ float gelu_tanh(float x) {
    // jax.nn.gelu(approximate=True), exp2 domain
    float x2 = x * x;
    float e = __builtin_amdgcn_exp2f(x * fmaf(-0.10294340397f, x2, -2.30220899f));
    return x * __builtin_amdgcn_rcpf(1.0f + e);
}

__device__ __forceinline__ float wave_sum(float s) {
#pragma unroll
    for (int off = 32; off; off >>= 1) s += __shfl_xor(s, off);
    return s;
}

// ---------- K0: small-weight precompute, one WAVE per reduction ----------
// wpack[lvl*256+k] = {W1[lvl,0,k], W1[lvl,1,k], b1[lvl,k], mean_h W2[lvl,k,h]}
__global__ __launch_bounds__(256) void prep_kernel(
        const float* __restrict__ W1, const float* __restrict__ b1,
        const float* __restrict__ W2, const float* __restrict__ b2,
        const float* __restrict__ Wo, const float* __restrict__ bo,
        const float* __restrict__ Wout, const float* __restrict__ bout,
        float4* __restrict__ wpack, float* __restrict__ b2m,
        float* __restrict__ wf, float* __restrict__ bf) {
    int wid  = (blockIdx.x * 256 + threadIdx.x) >> 6;
    int lane = threadIdx.x & 63;
    if (wid < 768) {
        const float* r = W2 + (size_t)wid * 128;
        float s = wave_sum(r[lane] + r[lane + 64]);
        if (lane == 0) {
            int lvl = wid >> 8, k = wid & 255;
            wpack[wid] = make_float4(W1[lvl * 512 + k], W1[lvl * 512 + 256 + k],
                                     b1[wid], s * (1.0f / 128.0f));
        }
    } else if (wid < 771) {
        int lvl = wid - 768;
        const float* r = b2 + lvl * 128;
        float s = wave_sum(r[lane] + r[lane + 64]);
        if (lane == 0) b2m[lvl] = s * (1.0f / 128.0f);
    } else if (wid < 1155) {
        int e = wid - 771;
        int h = e / 3, c = e - 3 * h;
        float s = wave_sum(fmaf(Wo[h * 128 + lane], Wout[lane * 3 + c],
                                Wo[h * 128 + 64 + lane] * Wout[(lane + 64) * 3 + c]));
        if (lane == 0) wf[e] = s;
    } else if (wid < 1158) {
        int c = wid - 1155;
        float s = wave_sum(fmaf(bo[lane], Wout[lane * 3 + c],
                                bo[lane + 64] * Wout[(lane + 64) * 3 + c]));
        if (lane == 0) bf[c] = s + bout[c];
    }
}

// ---------- K1: full wavelet pyramid for one (b,h) row, all in LDS; 512 threads ----------
__global__ __launch_bounds__(512) void wavelet_fused_kernel(
        const float* __restrict__ x, const float* __restrict__ Win,
        const float* __restrict__ b_in,
        const float* __restrict__ wlow, const float* __restrict__ whigh,
        const float4* __restrict__ wpack, const float* __restrict__ b2m,
        float* __restrict__ r0g) {
    __shared__ float cur[2048];
    __shared__ float aA[1024];
    __shared__ float pp0[1024];
    __shared__ float aB[512];
    __shared__ float pp1[512];
    __shared__ float pp2[256];
    __shared__ float r2s[512];
    __shared__ float r1s[1024];   // reused as S4 partial scratch (first 512) before S6
    int tid = threadIdx.x;
    int m = blockIdx.x;
    int b = m >> 7, h = m & 127;
    float w0 = Win[h], w1 = Win[128 + h], w2 = Win[256 + h];
    float bi = b_in[h];
    float wl[8], wh[8];
#pragma unroll
    for (int t = 0; t < 8; ++t) { wl[t] = wlow[t]; wh[t] = whigh[t]; }

    // S1: input projection row (4 elems/thread)
    const float* xr = x + (size_t)b * (CIN_ * N_);
    for (int idx = tid; idx < 2048; idx += 512) {
        float v = bi;
        v = fmaf(xr[idx], w0, v);
        v = fmaf(xr[N_ + idx], w1, v);
        v = fmaf(xr[2 * N_ + idx], w2, v);
        cur[idx] = v;
    }
    __syncthreads();

    // S2: level-0 DWT + MLP (2 coeffs/thread, L=2048)
    {
        float a2[2], d2[2], acc2[2];
#pragma unroll
        for (int u = 0; u < 2; ++u) {
            int i = tid + u * 512;
            int j0 = 2 * i - 4;
            float a = 0.f, d = 0.f;
#pragma unroll
            for (int t = 0; t < 8; ++t) {
                int j = j0 + t;
                float xv = ((unsigned)j < 2048u) ? cur[j] : 0.f;
                a = fmaf(xv, wl[7 - t], a);
                d = fmaf(xv, wh[7 - t], d);
            }
            a2[u] = a; d2[u] = d; aA[i] = a; acc2[u] = 0.f;
        }
#pragma unroll 4
        for (int kk = 0; kk < 256; ++kk) {
            float4 w = wpack[kk];
#pragma unroll
            for (int u = 0; u < 2; ++u) {
                float t = fmaf(a2[u], w.x, fmaf(d2[u], w.y, w.z));
                acc2[u] = fmaf(gelu_tanh(t), w.w, acc2[u]);
            }
        }
        float bb = b2m[0];
#pragma unroll
        for (int u = 0; u < 2; ++u) pp0[tid + u * 512] = acc2[u] + bb;
    }
    __syncthreads();

    // S3: level-1 DWT + MLP (1 coeff/thread, L=1024)
    {
        int i = tid;
        int j0 = 2 * i - 4;
        float a = 0.f, d = 0.f;
#pragma unroll
        for (int t = 0; t < 8; ++t) {
            int j = j0 + t;
            float xv = ((unsigned)j < 1024u) ? aA[j] : 0.f;
            a = fmaf(xv, wl[7 - t], a);
            d = fmaf(xv, wh[7 - t], d);
        }
        aB[i] = a;
        float acc = 0.f;
#pragma unroll 4
        for (int kk = 0; kk < 256; ++kk) {
            float4 w = wpack[256 + kk];
            float t = fmaf(a, w.x, fmaf(d, w.y, w.z));
            acc = fmaf(gelu_tanh(t), w.w, acc);
        }
        pp1[i] = acc + b2m[1];
    }
    __syncthreads();

    // S4: level-2 DWT + MLP (256 coeffs; both thread halves split the 256-k loop)
    {
        int i    = tid & 255;
        int half = tid >> 8;          // 0 or 1
        int j0 = 2 * i - 4;
        float a = 0.f, d = 0.f;
#pragma unroll
        for (int t = 0; t < 8; ++t) {
            int j = j0 + t;
            float xv = ((unsigned)j < 512u) ? aB[j] : 0.f;
            a = fmaf(xv, wl[7 - t], a);
            d = fmaf(xv, wh[7 - t], d);
        }
        float acc = 0.f;
        int kb = half * 128;
#pragma unroll 4
        for (int kk = 0; kk < 128; ++kk) {
            float4 w = wpack[512 + kb + kk];
            float t = fmaf(a, w.x, fmaf(d, w.y, w.z));
            acc = fmaf(gelu_tanh(t), w.w, acc);
        }
        r1s[tid] = acc;               // scratch: [half*256 + i]
    }
    __syncthreads();
    if (tid < 256) pp2[tid] = r1s[tid] + r1s[tid + 256] + b2m[2];
    __syncthreads();

    // S5: r2 = idwt(pp2, pp2), 512 outputs (1/thread), L=256
    {
        int ii = tid;
        int podd = ii & 1;
        int off0 = (ii >> 1) - 2 + podd;
        float r = 0.f;
#pragma unroll
        for (int s = 0; s < 4; ++s) {
            int idx = off0 + s;
            float av = ((unsigned)idx < 256u) ? pp2[idx] : 0.f;
            r = fmaf(av, wl[2 * s + podd] + wh[2 * s + podd], r);
        }
        r2s[ii] = r;
    }
    __syncthreads();

    // S6: r1 = idwt(r2s, pp1), 1024 outputs (2/thread), L=512
#pragma unroll
    for (int u = 0; u < 2; ++u) {
        int ii = tid + u * 512;
        int podd = ii & 1;
        int off0 = (ii >> 1) - 2 + podd;
        float r = 0.f;
#pragma unroll
        for (int s = 0; s < 4; ++s) {
            int idx = off0 + s;
            bool ok = (unsigned)idx < 512u;
            float av = ok ? r2s[idx] : 0.f;
            float dv = ok ? pp1[idx] : 0.f;
            r = fmaf(av, wl[2 * s + podd], r);
            r = fmaf(dv, wh[2 * s + podd], r);
        }
        r1s[ii] = r;
    }
    __syncthreads();

    // S7: r0 = idwt(r1s, pp0), 2048 outputs (4/thread), L=1024 -> global
    float* orow = r0g + (size_t)m * 2048;
#pragma unroll
    for (int u = 0; u < 4; ++u) {
        int ii = tid + u * 512;
        int podd = ii & 1;
        int off0 = (ii >> 1) - 2 + podd;
        float r = 0.f;
#pragma unroll
        for (int s = 0; s < 4; ++s) {
            int idx = off0 + s;
            bool ok = (unsigned)idx < 1024u;
            float av = ok ? r1s[idx] : 0.f;
            float dv = ok ? pp0[idx] : 0.f;
            r = fmaf(av, wl[2 * s + podd], r);
            r = fmaf(dv, wh[2 * s + podd], r);
        }
        orow[ii] = r;
    }
}

// ---------- K5: QKV projection, 8 rows/block (2x blocks, 2x shorter load chains) ----------
__global__ __launch_bounds__(384) void qkv_kernel(
        const float* __restrict__ r0,
        const float* __restrict__ Wq, const float* __restrict__ bq,
        const float* __restrict__ Wk, const float* __restrict__ bk,
        const float* __restrict__ Wv, const float* __restrict__ bv,
        float* __restrict__ qB, float* __restrict__ kB, float* __restrict__ vB) {
    int tid = threadIdx.x;
    int rowbase = blockIdx.x * 8;        // row = b*N + n, 1024 blocks
    int b  = rowbase >> 11;
    int n0 = rowbase & 2047;

    const float* W; const float* bias; float* dst; int jj;
    if (tid < 128)      { W = Wq; bias = bq; dst = qB; jj = tid; }
    else if (tid < 256) { W = Wk; bias = bk; dst = kB; jj = tid - 128; }
    else                { W = Wv; bias = bv; dst = vB; jj = tid - 256; }

    const float* abase = r0 + (size_t)b * (H_ * N_) + n0;
    float acc[8];
#pragma unroll
    for (int r = 0; r < 8; ++r) acc[r] = 0.f;
#pragma unroll 4
    for (int h = 0; h < 128; ++h) {
        float w = W[h * 128 + jj];
        const float* ar = abase + (size_t)h * N_;   // uniform -> s_load
#pragma unroll
        for (int r = 0; r < 8; ++r) acc[r] = fmaf(ar[r], w, acc[r]);
    }
    float bb = bias[jj];
    int head = jj >> 4, t = jj & 15;
    size_t obase = ((size_t)(b * 8 + head) * N_) * 16 + t;
#pragma unroll
    for (int r = 0; r < 8; ++r)
        dst[obase + (size_t)(n0 + r) * 16] = acc[r] + bb;
}

// ---------- K6: flash attention (round-9 proven): split-K, 4 q/lane, K+V LDS, defer-max ----------
#define DOT4(acc, qq, aa) do { acc = fmaf(qq.x, aa.x, acc); acc = fmaf(qq.y, aa.y, acc); \
                               acc = fmaf(qq.z, aa.z, acc); acc = fmaf(qq.w, aa.w, acc); } while (0)
#define SCALE4(oo, c)     do { oo.x *= c; oo.y *= c; oo.z *= c; oo.w *= c; } while (0)
#define AXPY4(oo, p, aa)  do { oo.x = fmaf(p, aa.x, oo.x); oo.y = fmaf(p, aa.y, oo.y); \
                               oo.z = fmaf(p, aa.z, oo.z); oo.w = fmaf(p, aa.w, oo.w); } while (0)

template<int KS>
__global__ __launch_bounds__(128, 2) void attn_kernel(
        const float* __restrict__ qb, const float* __restrict__ kb,
        const float* __restrict__ vb,
        float* __restrict__ part_o, float* __restrict__ part_ml) {
    __shared__ float4 kt4[512];   // 128 keys x 16 floats
    __shared__ float4 vt4[512];
    int tid   = threadIdx.x;
    int blk   = blockIdx.x;        // bh*(4*KS) + qblk*KS + split
    int split = blk % KS;
    int qblk  = (blk / KS) & 3;
    int bh    = blk / (4 * KS);

    const float4* ksrc = (const float4*)(kb + (size_t)bh * (N_ * 16));
    const float4* vsrc = (const float4*)(vb + (size_t)bh * (N_ * 16));
    const float sc = 0.25f * LOG2E;

    float4 q[4][4];
    float  m[4], l[4];
    float4 o[4][4];
#pragma unroll
    for (int qi = 0; qi < 4; ++qi) {
        const float4* qr = (const float4*)(qb + ((size_t)bh * N_ + qblk * 512 + qi * 128 + tid) * 16);
#pragma unroll
        for (int j = 0; j < 4; ++j) { q[qi][j] = qr[j]; SCALE4(q[qi][j], sc); }
        m[qi] = -3.0e38f; l[qi] = 0.f;
#pragma unroll
        for (int j = 0; j < 4; ++j) o[qi][j] = make_float4(0.f, 0.f, 0.f, 0.f);
    }

    int k0 = split * (N_ / KS);
    for (int t0 = k0; t0 < k0 + N_ / KS; t0 += 128) {
        __syncthreads();
        const float4* ks = ksrc + t0 * 4;
        const float4* vs = vsrc + t0 * 4;
#pragma unroll
        for (int u = 0; u < 4; ++u) {
            kt4[tid + u * 128] = ks[tid + u * 128];
            vt4[tid + u * 128] = vs[tid + u * 128];
        }
        __syncthreads();

        for (int c0 = 0; c0 < 128; c0 += 4) {
            float sv[4][4];
            float cm[4] = {-3.0e38f, -3.0e38f, -3.0e38f, -3.0e38f};
#pragma unroll
            for (int c = 0; c < 4; ++c) {
                int kr = (c0 + c) * 4;
                float4 k0v = kt4[kr], k1v = kt4[kr+1], k2v = kt4[kr+2], k3v = kt4[kr+3];
#pragma unroll
                for (int qi = 0; qi < 4; ++qi) {
                    float s0 = 0.f, s1 = 0.f;
                    DOT4(s0, q[qi][0], k0v); DOT4(s1, q[qi][1], k1v);
                    DOT4(s0, q[qi][2], k2v); DOT4(s1, q[qi][3], k3v);
                    sv[qi][c] = s0 + s1;
                    cm[qi] = fmaxf(cm[qi], sv[qi][c]);
                }
            }
            bool need = (cm[0] > m[0] + 8.f) || (cm[1] > m[1] + 8.f) ||
                        (cm[2] > m[2] + 8.f) || (cm[3] > m[3] + 8.f);
            if (__any(need)) {
#pragma unroll
                for (int qi = 0; qi < 4; ++qi) {
                    float mn = fmaxf(m[qi], cm[qi]);
                    float cr = __builtin_amdgcn_exp2f(m[qi] - mn);
                    l[qi] *= cr;
#pragma unroll
                    for (int j = 0; j < 4; ++j) SCALE4(o[qi][j], cr);
                    m[qi] = mn;
                }
            }
#pragma unroll
            for (int c = 0; c < 4; ++c) {
                int vr = (c0 + c) * 4;
                float4 v0 = vt4[vr], v1 = vt4[vr+1], v2 = vt4[vr+2], v3 = vt4[vr+3];
#pragma unroll
                for (int qi = 0; qi < 4; ++qi) {
                    float p = __builtin_amdgcn_exp2f(sv[qi][c] - m[qi]);
                    l[qi] += p;
                    AXPY4(o[qi][0], p, v0); AXPY4(o[qi][1], p, v1);
                    AXPY4(o[qi][2], p, v2); AXPY4(o[qi][3], p, v3);
                }
            }
        }
    }
#pragma unroll
    for (int qi = 0; qi < 4; ++qi) {
        int qg = bh * N_ + qblk * 512 + qi * 128 + tid;
        float4* po = (float4*)part_o + ((size_t)split * 65536 + qg) * 4;
        po[0] = o[qi][0]; po[1] = o[qi][1]; po[2] = o[qi][2]; po[3] = o[qi][3];
        ((float2*)part_ml)[(size_t)split * 65536 + qg] = make_float2(m[qi], l[qi]);
    }
}

// ---------- K6b: split-K combine fused with final projection ----------
template<int KS>
__global__ __launch_bounds__(128) void combine_final_kernel(
        const float* __restrict__ part_o, const float* __restrict__ part_ml,
        const float* __restrict__ wf, const float* __restrict__ bf,
        float* __restrict__ out) {
    __shared__ float ysh[16 * 129];
    int tid = threadIdx.x;
    int b = blockIdx.x >> 7, nb = blockIdx.x & 127;
    int head = tid >> 4, nl = tid & 15;
    int n = nb * 16 + nl;
    int qg = (b * 8 + head) * N_ + n;

    float m[KS], l[KS];
    float M = -3.0e38f;
#pragma unroll
    for (int s = 0; s < KS; ++s) {
        float2 ml = ((const float2*)part_ml)[(size_t)s * 65536 + qg];
        m[s] = ml.x; l[s] = ml.y;
        M = fmaxf(M, m[s]);
    }
    float w[KS], lt = 0.f;
#pragma unroll
    for (int s = 0; s < KS; ++s) {
        w[s] = __builtin_amdgcn_exp2f(m[s] - M);
        lt = fmaf(l[s], w[s], lt);
    }
    float inv = __builtin_amdgcn_rcpf(lt);
    float o[16];
#pragma unroll
    for (int j = 0; j < 16; ++j) o[j] = 0.f;
#pragma unroll
    for (int s = 0; s < KS; ++s) {
        const float4* po = (const float4*)part_o + ((size_t)s * 65536 + qg) * 4;
#pragma unroll
        for (int r = 0; r < 4; ++r) {
            float4 v = po[r];
            o[4*r+0] = fmaf(v.x, w[s], o[4*r+0]);
            o[4*r+1] = fmaf(v.y, w[s], o[4*r+1]);
            o[4*r+2] = fmaf(v.z, w[s], o[4*r+2]);
            o[4*r+3] = fmaf(v.w, w[s], o[4*r+3]);
        }
    }
    int col = head * 16;
#pragma unroll
    for (int j = 0; j < 16; ++j) ysh[nl * 129 + col + j] = o[j] * inv;
    __syncthreads();
    if (tid < 48) {
        int c = tid >> 4, nl2 = tid & 15;
        float acc = bf[c];
        const float* yr = ysh + nl2 * 129;
#pragma unroll 4
        for (int h = 0; h < 128; ++h) acc = fmaf(yr[h], wf[h * 3 + c], acc);
        out[((size_t)b * 3 + c) * N_ + nb * 16 + nl2] = acc;
    }
}

// ---------- launch ----------
extern "C" void kernel_launch(void* const* d_in, const int* in_sizes, int n_in,
                              void* d_out, int out_size, void* d_ws, size_t ws_size,
                              hipStream_t stream) {
    const float* x    = (const float*)d_in[0];
    const float* wlow = (const float*)d_in[1];
    const float* whigh= (const float*)d_in[2];
    const float* Win  = (const float*)d_in[3];
    const float* b_in = (const float*)d_in[4];
    const float* W1   = (const float*)d_in[5];
    const float* b1   = (const float*)d_in[6];
    const float* W2   = (const float*)d_in[7];
    const float* b2   = (const float*)d_in[8];
    const float* Wq   = (const float*)d_in[9];
    const float* bq   = (const float*)d_in[10];
    const float* Wk   = (const float*)d_in[11];
    const float* bk   = (const float*)d_in[12];
    const float* Wv   = (const float*)d_in[13];
    const float* bv   = (const float*)d_in[14];
    const float* Wo   = (const float*)d_in[15];
    const float* bo   = (const float*)d_in[16];
    const float* Wout = (const float*)d_in[17];
    const float* bout = (const float*)d_in[18];
    float* out = (float*)d_out;
    (void)in_sizes; (void)n_in; (void)out_size;

    float* ws = (float*)d_ws;
    // persistent: q/k/v buffers, each B*HEADS*N*dh = 1,048,576 floats
    float* qBuf  = ws;
    float* kBuf  = ws + 1048576;
    float* vBuf  = ws + 2097152;
    float* base2 = ws + 3145728;
    // r0 (dead after qkv) overlays the attention partials region
    float* r0    = base2;              // 1,048,576 floats

    // choose split-K by available workspace (constant across calls)
    const size_t need16 = (3145728ull + 16ull * 1048576 + 16ull * 131072 + 4096ull) * 4;
    const size_t need8  = (3145728ull +  8ull * 1048576 +  8ull * 131072 + 4096ull) * 4;
    int KS = (ws_size >= need16) ? 16 : ((ws_size >= need8) ? 8 : 4);

    float* part_o  = base2;                              // KS * 1048576 floats
    float* part_ml = base2 + (size_t)KS * 1048576;       // KS * 131072 floats
    float* smalls  = part_ml + (size_t)KS * 131072;
    float4* wpack = (float4*)smalls;                     // 768 float4 = 3072 floats
    float* b2m = smalls + 3072;                          // 3
    float* wf  = smalls + 3088;                          // 384
    float* bf  = smalls + 3472;                          // 3

    prep_kernel<<<290, 256, 0, stream>>>(W1, b1, W2, b2, Wo, bo, Wout, bout, wpack, b2m, wf, bf);

    wavelet_fused_kernel<<<512, 512, 0, stream>>>(x, Win, b_in, wlow, whigh,
                                                  wpack, b2m, r0);

    qkv_kernel<<<1024, 384, 0, stream>>>(r0, Wq, bq, Wk, bk, Wv, bv, qBuf, kBuf, vBuf);

    if (KS == 16) {
        attn_kernel<16><<<32 * 4 * 16, 128, 0, stream>>>(qBuf, kBuf, vBuf, part_o, part_ml);
        combine_final_kernel<16><<<512, 128, 0, stream>>>(part_o, part_ml, wf, bf, out);
    } else if (KS == 8) {
        attn_kernel<8><<<32 * 4 * 8, 128, 0, stream>>>(qBuf, kBuf, vBuf, part_o, part_ml);
        combine_final_kernel<8><<<512, 128, 0, stream>>>(part_o, part_ml, wf, bf, out);
    } else {
        attn_kernel<4><<<32 * 4 * 4, 128, 0, stream>>>(qBuf, kBuf, vBuf, part_o, part_ml);
        combine_final_kernel<4><<<512, 128, 0, stream>>>(part_o, part_ml, wf, bf, out);
    }
}